// Round 10
// baseline (1224.656 us; speedup 1.0000x reference)
//
#include <hip/hip_runtime.h>
#include <stdint.h>

#define B_N 16
#define S_N 256
#define H_N 512
#define V_N 32000
#define G4_N 2048
#define START_TOK 1
#define NBLK 16   // scan blocks (4 waves each, 64 wave-slots total)

typedef float f32x4 __attribute__((ext_vector_type(4)));
typedef int   i32x4 __attribute__((ext_vector_type(4)));
typedef unsigned short u16;
typedef u16 u16x4 __attribute__((ext_vector_type(4)));

static __device__ __forceinline__ u16 f2bf(float f) {
  unsigned u = __float_as_uint(f);
  return (u16)((u + 0x7fffu + ((u >> 16) & 1u)) >> 16);  // RNE
}
static __device__ __forceinline__ float bf2f(u16 b) {
  return __uint_as_float(((unsigned)b) << 16);
}

// MFMA: A pinned in AGPRs, B/acc in VGPRs (gfx950 unified file).
static __device__ __forceinline__ void mfma_av(f32x4& d, i32x4 a, i32x4 b) {
  asm("v_mfma_f32_16x16x32_bf16 %0, %1, %2, %0" : "+v"(d) : "a"(a), "v"(b));
}
static __device__ __forceinline__ void mfma_vv(f32x4& d, i32x4 a, i32x4 b) {
  asm("v_mfma_f32_16x16x32_bf16 %0, %1, %2, %0" : "+v"(d) : "v"(a), "v"(b));
}

static __device__ __forceinline__ void async16(const void* g, void* l) {
  __builtin_amdgcn_global_load_lds((const __attribute__((address_space(1))) unsigned*)g,
                                   (__attribute__((address_space(3))) unsigned*)l,
                                   16, 0, 0);
}

// LLC-direct (cross-XCD coherent) 16B load. "memory" clobber prevents the
// compiler from hoisting these above atomic poll loops (the v6/v8 bug);
// strictly safer than r7's version, behavior behind barriers identical.
static __device__ __forceinline__ i32x4 llc16(const void* p) {
  i32x4 v;
  asm volatile("global_load_dwordx4 %0, %1, off sc0 sc1"
               : "=v"(v) : "v"(p) : "memory");
  return v;
}

// fast transcendentals (TRANS->VALU hazard covered by s_nop 1)
static __device__ __forceinline__ float vexp2(float x) {
  float r; asm("v_exp_f32 %0, %1\n\ts_nop 1" : "=v"(r) : "v"(x)); return r;
}
static __device__ __forceinline__ float vrcp(float x) {
  float r; asm("v_rcp_f32 %0, %1\n\ts_nop 1" : "=v"(r) : "v"(x)); return r;
}
static __device__ __forceinline__ float fsig(float x) {
  return vrcp(1.f + vexp2(-1.44269504f * x));
}
static __device__ __forceinline__ float ftanh(float x) {
  return 1.f - 2.f * vrcp(1.f + vexp2(2.88539008f * x));
}

// ---------------- prep kernels ----------------

__global__ void cast_bf16_kernel(const float* __restrict__ in, u16* __restrict__ out, int n4) {
  int i = blockIdx.x * blockDim.x + threadIdx.x;
  int stride = gridDim.x * blockDim.x;
  for (int q = i; q < n4; q += stride) {
    f32x4 v = *(const f32x4*)(in + 4l * q);
    u16x4 o;
    o.x = f2bf(v.x); o.y = f2bf(v.y); o.z = f2bf(v.z); o.w = f2bf(v.w);
    *(u16x4*)(out + 4l * q) = o;
  }
}

// zero ctr + stage h0 into plane slot 0 (packed hi/lo bf16 unit-pairs).
__global__ void init_scan_kernel(const float* __restrict__ h0, unsigned* __restrict__ Phi,
                                 unsigned* __restrict__ Plo, unsigned* __restrict__ ctr) {
  int i = blockIdx.x * blockDim.x + threadIdx.x;   // 0..4095
  if (i < 256) ctr[i] = 0u;
  float f0 = h0[2 * i];
  float f1 = h0[2 * i + 1];
  u16 h0a = f2bf(f0), h1a = f2bf(f1);
  u16 l0a = f2bf(f0 - bf2f(h0a)), l1a = f2bf(f1 - bf2f(h1a));
  Phi[i] = (unsigned)h0a | ((unsigned)h1a << 16);
  Plo[i] = (unsigned)l0a | ((unsigned)l1a << 16);
}

// ---------------- bf16 MFMA GEMM, 128x128 (gather path; round-1 verified) ----

__global__ __launch_bounds__(256)
void gemm_bf16_gather(const u16* __restrict__ A, const u16* __restrict__ Bm,
                      float* __restrict__ C,
                      const float* __restrict__ bias0, const float* __restrict__ bias1,
                      const int* __restrict__ target) {
  constexpr int K = H_N;  // 512
  __shared__ u16 Alds[128 * 32];
  __shared__ u16 Blds[128 * 32];
  const int tid  = threadIdx.x;
  const int lane = tid & 63;
  const int wq   = tid >> 6;
  const int mbase = blockIdx.y * 128;
  const int nbase = blockIdx.x * 128;

  const int r     = tid >> 2;
  const int off16 = (tid & 3) << 4;

  long arow0, arow1;
  {
    int m0 = mbase + r, m1 = mbase + 64 + r;
    int t0 = m0 & (S_N - 1), b0 = m0 >> 8;
    int t1 = m1 & (S_N - 1), b1 = m1 >> 8;
    arow0 = (t0 == 0) ? START_TOK : target[b0 * S_N + t0 - 1];
    arow1 = (t1 == 0) ? START_TOK : target[b1 * S_N + t1 - 1];
  }
  const long brow0 = nbase + r, brow1 = nbase + 64 + r;

  char* AldsB = (char*)Alds;
  char* BldsB = (char*)Blds;
  const char* Ab = (const char*)A;
  const char* Bb = (const char*)Bm;
  const int ldsw = wq << 10;

  const int wm   = (wq >> 1) << 6;
  const int wn   = (wq & 1) << 6;
  const int lrow = lane & 15;
  const int lk   = (lane >> 4) << 3;

  f32x4 acc[4][4] = {};

  for (int kt = 0; kt < K / 32; ++kt) {
    __syncthreads();
    const long kb = kt * 64 + off16;
    async16(Ab + arow0 * (K * 2) + kb, AldsB + ldsw);
    async16(Ab + arow1 * (K * 2) + kb, AldsB + 4096 + ldsw);
    async16(Bb + brow0 * (K * 2) + kb, BldsB + ldsw);
    async16(Bb + brow1 * (K * 2) + kb, BldsB + 4096 + ldsw);
    __syncthreads();

    i32x4 a[4], b[4];
    #pragma unroll
    for (int mi = 0; mi < 4; ++mi)
      a[mi] = *(const i32x4*)(AldsB + (((wm + mi * 16 + lrow) << 5) + lk) * 2);
    #pragma unroll
    for (int ni = 0; ni < 4; ++ni)
      b[ni] = *(const i32x4*)(BldsB + (((wn + ni * 16 + lrow) << 5) + lk) * 2);
    #pragma unroll
    for (int mi = 0; mi < 4; ++mi)
      #pragma unroll
      for (int ni = 0; ni < 4; ++ni)
        mfma_vv(acc[mi][ni], a[mi], b[ni]);
  }
  asm volatile("s_nop 7\n\ts_nop 7");

  const int rbase = (lane >> 4) << 2;
  #pragma unroll
  for (int ni = 0; ni < 4; ++ni) {
    const int col = nbase + wn + ni * 16 + lrow;
    float bv = bias0[col] + bias1[col];
    #pragma unroll
    for (int mi = 0; mi < 4; ++mi) {
      const int row = mbase + wm + mi * 16 + rbase;
      f32x4 v = acc[mi][ni];
      // scatter to xWt[s][wid][b][ul][g]; rows row..row+3 = s..s+3 (same b)
      int b  = row >> 8, s0 = row & (S_N - 1);
      int ug = col & 511, g = col >> 9;
      size_t base = (((size_t)s0 * 64 + (ug >> 3)) * 16 + b) * 32 + (ug & 7) * 4 + g;
      C[base]         = v.x + bv;
      C[base + 32768] = v.y + bv;
      C[base + 65536] = v.z + bv;
      C[base + 98304] = v.w + bv;
    }
  }
}

// ---------------- bf16 MFMA GEMM, 128(M) x 256(N) tile (logits path) --------
// Same staging algebra as the 128x128 kernel (wave-chunk LDS mapping), with
// the A-tile reused across a 2x wider N-tile: operand traffic -25%, half the
// blocks. acc[4][8] (~200 VGPR) -> __launch_bounds__(256,1) to avoid spill.

__global__ __launch_bounds__(256, 1)
void gemm_bf16_logits(const u16* __restrict__ A, const u16* __restrict__ Bm,
                      float* __restrict__ C, const float* __restrict__ bias0) {
  constexpr int K = H_N;    // 512
  constexpr int N = V_N;    // 32000
  __shared__ u16 Alds[128 * 32];   //  8 KB
  __shared__ u16 Blds[256 * 32];   // 16 KB
  const int tid  = threadIdx.x;
  const int lane = tid & 63;
  const int wq   = tid >> 6;
  const int mbase = blockIdx.y * 128;
  const int nbase = blockIdx.x * 256;

  const int r     = tid >> 2;          // 0..63
  const int off16 = (tid & 3) << 4;

  const long arow0 = mbase + r, arow1 = mbase + 64 + r;

  char* AldsB = (char*)Alds;
  char* BldsB = (char*)Blds;
  const char* Ab = (const char*)A;
  const char* Bb = (const char*)Bm;
  const int ldsw = wq << 10;

  const int wm   = (wq >> 1) << 6;     // 0 / 64
  const int wn   = (wq & 1) << 7;      // 0 / 128
  const int lrow = lane & 15;
  const int lk   = (lane >> 4) << 3;

  f32x4 acc[4][8] = {};

  for (int kt = 0; kt < K / 32; ++kt) {
    __syncthreads();
    const long kb = kt * 64 + off16;
    async16(Ab + arow0 * (K * 2) + kb, AldsB + ldsw);
    async16(Ab + arow1 * (K * 2) + kb, AldsB + 4096 + ldsw);
    #pragma unroll
    for (int q = 0; q < 4; ++q)
      async16(Bb + (long)(nbase + q * 64 + r) * (K * 2) + kb,
              BldsB + q * 4096 + ldsw);
    __syncthreads();

    i32x4 a[4], b[8];
    #pragma unroll
    for (int mi = 0; mi < 4; ++mi)
      a[mi] = *(const i32x4*)(AldsB + (((wm + mi * 16 + lrow) << 5) + lk) * 2);
    #pragma unroll
    for (int ni = 0; ni < 8; ++ni)
      b[ni] = *(const i32x4*)(BldsB + (((wn + ni * 16 + lrow) << 5) + lk) * 2);
    #pragma unroll
    for (int mi = 0; mi < 4; ++mi)
      #pragma unroll
      for (int ni = 0; ni < 8; ++ni)
        mfma_vv(acc[mi][ni], a[mi], b[ni]);
  }
  asm volatile("s_nop 7\n\ts_nop 7");

  const int rbase = (lane >> 4) << 2;
  #pragma unroll
  for (int ni = 0; ni < 8; ++ni) {
    const int col = nbase + wn + ni * 16 + lrow;
    float bv = bias0[col];
    #pragma unroll
    for (int mi = 0; mi < 4; ++mi) {
      const int row = mbase + wm + mi * 16 + rbase;
      f32x4 v = acc[mi][ni];
      C[(long)(row + 0) * N + col] = v.x + bv;
      C[(long)(row + 1) * N + col] = v.y + bv;
      C[(long)(row + 2) * N + col] = v.z + bv;
      C[(long)(row + 3) * N + col] = v.w + bv;
    }
  }
}

// ---------------- cooperative LSTM scan (r7-exact; twice-proven sync) -------
// release: plane stores -> __syncthreads (vmcnt(0) drain) -> tid0 fetch_add
//          ctr[s] + poll ctr[s]==NBLK -> __syncthreads -> stage -> __syncthreads.
// Per-step ctr word, zeroed each launch by init kernel -> replay-determinism.

__global__ __launch_bounds__(256, 1)
void lstm_scan_coop(const float* __restrict__ xWt, const u16* __restrict__ Whh16,
                    const float* __restrict__ c0, unsigned* __restrict__ Phi,
                    unsigned* __restrict__ Plo, unsigned* __restrict__ ctr,
                    unsigned* __restrict__ hs32) {
  __shared__ __align__(16) u16 hl_hi[B_N * H_N];   // 16 KB, swizzled
  __shared__ __align__(16) u16 hl_lo[B_N * H_N];   // 16 KB, swizzled

  const int blk  = blockIdx.x;
  const int tid  = threadIdx.x;
  const int lane = tid & 63;
  const int wv   = tid >> 6;            // 0..3
  const int wid  = blk * 4 + wv;        // 0..63 (global wave id = unit group)
  const int fr   = lane & 15;
  const int ksub = lane >> 4;           // 0..3
  const int b    = fr;                  // batch (B-operand column)
  char* hiB = (char*)hl_hi;
  char* loB = (char*)hl_lo;

  // ---- A fragments (W slice) into AGPRs, resident across all 256 steps ----
  // A-row ar <-> gate (ar&3), unit wid*8 + t*4 + (ar>>2)
  i32x4 afr[2][16];
  {
    const char* Wb = (const char*)Whh16;
    #pragma unroll
    for (int t = 0; t < 2; ++t) {
      long grow = (long)(fr & 3) * H_N + wid * 8 + t * 4 + (fr >> 2);
      const char* rowp = Wb + grow * (H_N * 2) + ksub * 16;
      #pragma unroll
      for (int kt = 0; kt < 16; ++kt)
        afr[t][kt] = *(const i32x4*)(rowp + kt * 64);
    }
  }

  // lane-local cell state for units ua = wid*8+ksub, ub = ua+4
  const int ua = wid * 8 + ksub;
  const int ub = ua + 4;
  float ca = c0[b * H_N + ua];
  float cb = c0[b * H_N + ub];

  const bool stlane = ((ksub & 1) == 0);       // lanes that emit packed stores
  const int  pua    = wid * 4 + (ksub >> 1);   // unit-pair index for (ua,ua+1)

  // ---- stage h^0 planes from global slot 0 (init-written) ----
  {
    i32x4 th[4], tl[4];
    #pragma unroll
    for (int q = 0; q < 4; ++q) {
      int cidx = (q * 256 + tid) * 4;
      th[q] = llc16(Phi + cidx);
      tl[q] = llc16(Plo + cidx);
    }
    asm volatile("s_waitcnt vmcnt(0)" ::: "memory");
    __builtin_amdgcn_sched_barrier(0);
    #pragma unroll
    for (int q = 0; q < 4; ++q) {
      int cidx = (q * 256 + tid) * 4;
      int bb = cidx >> 8, j = cidx & 255;
      unsigned wa = (unsigned)(bb * 1024 + j * 4) ^ ((unsigned)(bb & 7) << 4);
      *(i32x4*)(hiB + wa) = th[q];
      *(i32x4*)(loB + wa) = tl[q];
    }
  }
  __syncthreads();

  // B-fragment addressing (r4/r7-proven swizzled layout)
  const unsigned hbase = (unsigned)(fr * 1024);
  const unsigned hswz  = ((unsigned)(fr & 7)) << 4;
  const unsigned k16   = ((unsigned)ksub) << 4;

  for (int s = 0; s < S_N; ++s) {
    // xW for this step (plain cached loads, contiguous per wave)
    const float* xp = xWt + ((size_t)s * 64 + wid) * 512 + b * 32;
    f32x4 xwa = *(const f32x4*)(xp + ksub * 4);
    f32x4 xwb = *(const f32x4*)(xp + 16 + ksub * 4);

    // gates = W_slice * (h_hi + h_lo), 4 independent MFMA chains
    f32x4 a00 = {0.f,0.f,0.f,0.f}, a01 = {0.f,0.f,0.f,0.f};
    f32x4 a10 = {0.f,0.f,0.f,0.f}, a11 = {0.f,0.f,0.f,0.f};
    #pragma unroll
    for (int kt = 0; kt < 16; ++kt) {
      unsigned off = (hbase + (unsigned)(kt * 64) + k16) ^ hswz;
      i32x4 bhi = *(const i32x4*)(hiB + off);
      i32x4 blo = *(const i32x4*)(loB + off);
      mfma_av(a00, afr[0][kt], bhi);
      mfma_av(a10, afr[1][kt], bhi);
      mfma_av(a01, afr[0][kt], blo);
      mfma_av(a11, afr[1][kt], blo);
    }
    asm volatile("s_nop 7\n\ts_nop 7\n\ts_nop 7");  // MFMA->VALU hazard

    f32x4 ga = a00 + a01;   // {i,f,g,o} for (ua, b)
    f32x4 gb = a10 + a11;   // {i,f,g,o} for (ub, b)

    float gia = fsig(ga.x + xwa.x), gfa = fsig(ga.y + xwa.y);
    float gga = ftanh(ga.z + xwa.z), goa = fsig(ga.w + xwa.w);
    ca = gfa * ca + gia * gga;
    float ha = goa * ftanh(ca);

    float gib = fsig(gb.x + xwb.x), gfb = fsig(gb.y + xwb.y);
    float ggb = ftanh(gb.z + xwb.z), gob = fsig(gb.w + xwb.w);
    cb = gfb * cb + gib * ggb;
    float hb = gob * ftanh(cb);

    u16 ha16 = f2bf(ha), hb16 = f2bf(hb);
    u16 la16 = f2bf(ha - bf2f(ha16));
    u16 lb16 = f2bf(hb - bf2f(hb16));

    // pack unit-pairs: even-ksub lane holds unit u, partner (lane^16) u+1
    unsigned pha = (unsigned)ha16 | ((unsigned)__shfl_xor((int)(unsigned)ha16, 16) << 16);
    unsigned phb = (unsigned)hb16 | ((unsigned)__shfl_xor((int)(unsigned)hb16, 16) << 16);
    unsigned pla = (unsigned)la16 | ((unsigned)__shfl_xor((int)(unsigned)la16, 16) << 16);
    unsigned plb = (unsigned)lb16 | ((unsigned)__shfl_xor((int)(unsigned)lb16, 16) << 16);

    if (stlane) {
      // hs output [b][s][u] as u32 pairs (plain cached stores)
      hs32[((size_t)b * S_N + s) * (H_N / 2) + pua]     = pha;
      hs32[((size_t)b * S_N + s) * (H_N / 2) + pua + 2] = phb;
      if (s < S_N - 1) {
        const size_t pb = ((size_t)((s + 1) & 1) * B_N + b) * (H_N / 2);
        __hip_atomic_store(&Phi[pb + pua],     pha, __ATOMIC_RELAXED, __HIP_MEMORY_SCOPE_AGENT);
        __hip_atomic_store(&Phi[pb + pua + 2], phb, __ATOMIC_RELAXED, __HIP_MEMORY_SCOPE_AGENT);
        __hip_atomic_store(&Plo[pb + pua],     pla, __ATOMIC_RELAXED, __HIP_MEMORY_SCOPE_AGENT);
        __hip_atomic_store(&Plo[pb + pua + 2], plb, __ATOMIC_RELAXED, __HIP_MEMORY_SCOPE_AGENT);
      }
    }

    if (s == S_N - 1) break;

    __syncthreads();  // compiler emits s_waitcnt vmcnt(0) before s_barrier
    if (tid == 0) {
      __hip_atomic_fetch_add(&ctr[s], 1u, __ATOMIC_RELAXED, __HIP_MEMORY_SCOPE_AGENT);
      while (__hip_atomic_load(&ctr[s], __ATOMIC_RELAXED, __HIP_MEMORY_SCOPE_AGENT) < NBLK)
        __builtin_amdgcn_s_sleep(1);
    }
    __syncthreads();

    // stage h^{s+1} planes: LLC-direct copy into swizzled LDS
    {
      const unsigned slotoff = (unsigned)(((s + 1) & 1) * 4096);
      i32x4 th[4], tl[4];
      #pragma unroll
      for (int q = 0; q < 4; ++q) {
        int cidx = (q * 256 + tid) * 4;
        th[q] = llc16(Phi + slotoff + cidx);
        tl[q] = llc16(Plo + slotoff + cidx);
      }
      asm volatile("s_waitcnt vmcnt(0)" ::: "memory");
      __builtin_amdgcn_sched_barrier(0);
      #pragma unroll
      for (int q = 0; q < 4; ++q) {
        int cidx = (q * 256 + tid) * 4;
        int bb = cidx >> 8, j = cidx & 255;
        unsigned wa = (unsigned)(bb * 1024 + j * 4) ^ ((unsigned)(bb & 7) << 4);
        *(i32x4*)(hiB + wa) = th[q];
        *(i32x4*)(loB + wa) = tl[q];
      }
    }
    __syncthreads();
  }
}

// ---------------- launcher ----------------

extern "C" void kernel_launch(void* const* d_in, const int* in_sizes, int n_in,
                              void* d_out, int out_size, void* d_ws, size_t ws_size,
                              hipStream_t stream) {
  const int*   target = (const int*)  d_in[0];
  const float* h0     = (const float*)d_in[1];
  const float* c0     = (const float*)d_in[2];
  const float* emb    = (const float*)d_in[3];
  const float* W_ih   = (const float*)d_in[4];
  const float* W_hh   = (const float*)d_in[5];
  const float* b_ih   = (const float*)d_in[6];
  const float* b_hh   = (const float*)d_in[7];
  const float* out_b  = (const float*)d_in[8];
  float* out = (float*)d_out;

  char* ws = (char*)d_ws;
  u16*      E16   = (u16*)     (ws);              // V*H bf16        32,768,000 B
  u16*      Wih16 = (u16*)     (ws + 32768000);   // 4H*H bf16        2,097,152 B
  u16*      Whh16 = (u16*)     (ws + 34865152);   // 4H*H bf16        2,097,152 B
  float*    xWt   = (float*)   (ws + 36962304);   // B*S*4H f32      33,554,432 B
  u16*      hs16  = (u16*)     (ws + 70516736);   // B*S*H bf16       4,194,304 B
  unsigned* Phi   = (unsigned*)(ws + 74711040);   // 2*B*H/2 u32         32,768 B
  unsigned* Plo   = (unsigned*)(ws + 74743808);   // 2*B*H/2 u32         32,768 B
  unsigned* ctr   = (unsigned*)(ws + 74776576);   // 256 u32              1,024 B
  (void)ws_size; (void)in_sizes; (void)n_in; (void)out_size;

  cast_bf16_kernel<<<2048, 256, 0, stream>>>(emb,  E16,   (V_N * H_N) / 4);
  cast_bf16_kernel<<<1024, 256, 0, stream>>>(W_ih, Wih16, (G4_N * H_N) / 4);
  cast_bf16_kernel<<<1024, 256, 0, stream>>>(W_hh, Whh16, (G4_N * H_N) / 4);
  init_scan_kernel<<<16, 256, 0, stream>>>(h0, Phi, Plo, ctr);

  // xWt[s][wid][b][ul][g] = (emb[tokens] @ W_ih^T + b_ih + b_hh), scattered
  gemm_bf16_gather<<<dim3(G4_N / 128, (B_N * S_N) / 128), 256, 0, stream>>>(
      E16, Wih16, xWt, b_ih, b_hh, target);

  lstm_scan_coop<<<NBLK, 256, 0, stream>>>(xWt, Whh16, c0, Phi, Plo, ctr,
                                           (unsigned*)hs16);

  // logits = hs @ E^T + out_bias  (128x256 tile: A reused across 2x N)
  gemm_bf16_logits<<<dim3(V_N / 256, (B_N * S_N) / 128), 256, 0, stream>>>(
      hs16, E16, out, out_b);
}